// Round 1
// baseline (2086.447 us; speedup 1.0000x reference)
//
#include <hip/hip_runtime.h>
#include <math.h>

#define TM 16
#define ATT0_BLOCKS 256

__device__ __forceinline__ float gelu_f(float x) {
    return 0.5f * x * (1.0f + erff(x * 0.70710678118654752f));
}

__device__ __forceinline__ float pe_val(int pos, int j, int D) {
    int i2 = j & ~1;
    float freq = expf(-9.210340371976184f * (float)i2 / (float)D); // -ln(10000)
    float arg = (float)pos * freq;
    return (j & 1) ? cosf(arg) : sinf(arg);
}

// ---------------------------------------------------------------------------
// K1: tiny setup — q rows (PositionalMLP), bias rows, c2/c3 constant vectors
// blocks: 0..1 q rows | 2..10 bias rows | 11..12 c2 | 13..21 c3
// ---------------------------------------------------------------------------
__global__ __launch_bounds__(256) void k_small(
    const float* __restrict__ qW1, const float* __restrict__ qb1,
    const float* __restrict__ qW2, const float* __restrict__ qb2,
    const float* __restrict__ bW1, const float* __restrict__ bb1,
    const float* __restrict__ bW2, const float* __restrict__ bb2,
    const float* __restrict__ m2W1, const float* __restrict__ m2b1,
    const float* __restrict__ m3W1, const float* __restrict__ m3b1,
    float* __restrict__ q01, float* __restrict__ ball,
    float* __restrict__ c2, float* __restrict__ c3)
{
    __shared__ float pe[256];
    __shared__ float h[256];
    int b = blockIdx.x, tid = threadIdx.x;
    if (b < 11) {
        int pos = (b < 2) ? b : (b - 2);
        if (tid < 64) pe[tid] = pe_val(pos, tid, 64);
        __syncthreads();
        const float* W1 = (b < 2) ? qW1 : bW1;
        const float* b1 = (b < 2) ? qb1 : bb1;
        const float* W2 = (b < 2) ? qW2 : bW2;
        const float* b2 = (b < 2) ? qb2 : bb2;
        float acc = b1[tid];
        for (int d = 0; d < 64; ++d) acc += pe[d] * W1[d * 256 + tid];
        h[tid] = gelu_f(acc);
        __syncthreads();
        float acc2 = b2[tid];
        for (int d = 0; d < 256; ++d) acc2 += h[d] * W2[d * 256 + tid];
        if (b < 2) q01[b * 256 + tid] = acc2;
        else ball[(b - 2) * 256 + tid] = acc2;
    } else {
        int pos; const float* W1; const float* b1; float* dst;
        if (b < 13) { pos = b - 11; W1 = m2W1; b1 = m2b1; dst = c2 + pos * 256; }
        else        { pos = b - 13; W1 = m3W1; b1 = m3b1; dst = c3 + pos * 256; }
        pe[tid] = pe_val(pos, tid, 256);
        __syncthreads();
        float acc = b1[tid];
        for (int d = 0; d < 256; ++d) acc += pe[d] * W1[(256 + d) * 256 + tid];
        dst[tid] = acc;
    }
}

// ---------------------------------------------------------------------------
// LN over a [TM][256] tile: A -> B, stats via P/MV scratch. Caller syncs after.
// ---------------------------------------------------------------------------
__device__ __forceinline__ void ln_tile(const float* A, float* B, float* P, float* MV,
                                        const float* __restrict__ g,
                                        const float* __restrict__ bb, int tid)
{
    {
        int r = tid >> 4, l = tid & 15;
        float s = 0.f, sq = 0.f;
        #pragma unroll
        for (int i = 0; i < 16; ++i) { float v = A[r * 256 + l + i * 16]; s += v; sq += v * v; }
        P[r * 32 + l] = s; P[r * 32 + 16 + l] = sq;
    }
    __syncthreads();
    if (tid < TM) {
        float s = 0.f, sq = 0.f;
        #pragma unroll
        for (int i = 0; i < 16; ++i) { s += P[tid * 32 + i]; sq += P[tid * 32 + 16 + i]; }
        float mean = s * (1.f / 256.f);
        float var = sq * (1.f / 256.f) - mean * mean;
        MV[tid * 2] = mean; MV[tid * 2 + 1] = rsqrtf(var + 1e-5f);
    }
    __syncthreads();
    float gg = g[tid], bv = bb[tid];
    #pragma unroll
    for (int r = 0; r < TM; ++r)
        B[r * 256 + tid] = (A[r * 256 + tid] - MV[r * 2]) * MV[r * 2 + 1] * gg + bv;
}

// ---------------------------------------------------------------------------
// Register-tiled GEMM stage: this thread (rg,cg) accumulates
//   acc{0,1}[i] = sum_d SRC[rg*8+i][d] * W[d*ldw + cg*2 + {0,1}]
// SRC is an LDS tile [TM][256] (16B aligned), W is row-major global.
// ---------------------------------------------------------------------------
__device__ __forceinline__ void gemm_tile(const float* SRC, const float* __restrict__ W,
                                          int ldw, int rg, int cg,
                                          float acc0[8], float acc1[8])
{
    const float4* B4 = (const float4*)SRC;
    #pragma unroll
    for (int i = 0; i < 8; ++i) { acc0[i] = 0.f; acc1[i] = 0.f; }
    for (int d4 = 0; d4 < 64; ++d4) {
        float4 bv[8];
        #pragma unroll
        for (int i = 0; i < 8; ++i) bv[i] = B4[(rg * 8 + i) * 64 + d4];
        #pragma unroll
        for (int k = 0; k < 4; ++k) {
            const float2 w = *(const float2*)&W[(d4 * 4 + k) * ldw + cg * 2];
            #pragma unroll
            for (int i = 0; i < 8; ++i) {
                float b = (k == 0) ? bv[i].x : (k == 1) ? bv[i].y : (k == 2) ? bv[i].z : bv[i].w;
                acc0[i] = fmaf(b, w.x, acc0[i]);
                acc1[i] = fmaf(b, w.y, acc1[i]);
            }
        }
    }
}

// ---------------------------------------------------------------------------
// K2: per-node fused  x1 = x + mlp1(ln(x));  v = x1@vW+vb;  logits = q·(x1@kW+kb)
// ---------------------------------------------------------------------------
__global__ __launch_bounds__(256) void k_node(
    const float* __restrict__ x,
    const float* __restrict__ m1W1, const float* __restrict__ m1b1,
    const float* __restrict__ m1W2, const float* __restrict__ m1b2,
    const float* __restrict__ n1g, const float* __restrict__ n1b,
    const float* __restrict__ kW, const float* __restrict__ kb,
    const float* __restrict__ vW, const float* __restrict__ vb,
    const float* __restrict__ q01,
    float* __restrict__ v_out, float* __restrict__ lg0, float* __restrict__ lg1, int N)
{
    __shared__ __align__(16) float S[TM * 768 + TM * 32 + TM * 2];
    float* A = S;                 // x tile -> x1
    float* B = S + TM * 256;      // ln tile; later k-tile low half
    float* C = S + TM * 512;      // h tile; later k-tile high half
    float* P = S + TM * 768;
    float* MV = S + TM * 800;
    float* KT = B;                // [TM][512] spans B..C

    int tid = threadIdx.x;
    int rg = tid >> 7, cg = tid & 127;
    int row0 = blockIdx.x * TM;

    for (int r = 0; r < TM; ++r) {
        int n = row0 + r;
        A[r * 256 + tid] = (n < N) ? x[(size_t)n * 256 + tid] : 0.f;
    }
    __syncthreads();
    ln_tile(A, B, P, MV, n1g, n1b, tid);
    __syncthreads();

    float acc0[8], acc1[8];
    // mlp1 stage 1: C = gelu(B @ m1W1 + b1)
    gemm_tile(B, m1W1, 256, rg, cg, acc0, acc1);
    {
        float b0 = m1b1[cg * 2], b1v = m1b1[cg * 2 + 1];
        #pragma unroll
        for (int i = 0; i < 8; ++i) {
            int r = rg * 8 + i;
            C[r * 256 + cg * 2]     = gelu_f(acc0[i] + b0);
            C[r * 256 + cg * 2 + 1] = gelu_f(acc1[i] + b1v);
        }
    }
    __syncthreads();
    // mlp1 stage 2: A += C @ m1W2 + b2
    gemm_tile(C, m1W2, 256, rg, cg, acc0, acc1);
    {
        float b0 = m1b2[cg * 2], b1v = m1b2[cg * 2 + 1];
        #pragma unroll
        for (int i = 0; i < 8; ++i) {
            int r = rg * 8 + i;
            A[r * 256 + cg * 2]     += acc0[i] + b0;
            A[r * 256 + cg * 2 + 1] += acc1[i] + b1v;
        }
    }
    __syncthreads();
    // k projection into KT [TM][512]
    for (int half = 0; half < 2; ++half) {
        gemm_tile(A, kW + half * 256, 512, rg, cg, acc0, acc1);
        int col = half * 256 + cg * 2;
        float b0 = kb[col], b1v = kb[col + 1];
        #pragma unroll
        for (int i = 0; i < 8; ++i) {
            int r = rg * 8 + i;
            KT[r * 512 + col]     = acc0[i] + b0;
            KT[r * 512 + col + 1] = acc1[i] + b1v;
        }
    }
    // v projection -> global (reads A only; KT writes already done by this thread)
    gemm_tile(A, vW, 256, rg, cg, acc0, acc1);
    {
        float b0 = vb[cg * 2], b1v = vb[cg * 2 + 1];
        #pragma unroll
        for (int i = 0; i < 8; ++i) {
            int n = row0 + rg * 8 + i;
            if (n < N) {
                v_out[(size_t)n * 256 + cg * 2]     = acc0[i] + b0;
                v_out[(size_t)n * 256 + cg * 2 + 1] = acc1[i] + b1v;
            }
        }
    }
    __syncthreads();
    // logits: 16 rows x 8 heads x {q0·k0, q1·k1}
    {
        int r = tid >> 4, sub = tid & 15;
        int which = sub >> 3, h = sub & 7;
        const float* q = q01 + which * 256 + h * 32;
        const float* kk = KT + r * 512 + which * 256 + h * 32;
        float acc = 0.f;
        #pragma unroll
        for (int d = 0; d < 32; ++d) acc += q[d] * kk[d];
        acc *= 0.17677669529663687f; // 1/sqrt(32)
        int n = row0 + r;
        if (n < N) (which ? lg1 : lg0)[(size_t)n * 8 + h] = acc;
    }
}

// ---------------------------------------------------------------------------
// K3: order-0 attention partials (deterministic, no atomics)
// part[b][0..255] = sum exp(lg0)*v ; part[b][256+h] = sum exp(lg0)
// ---------------------------------------------------------------------------
__global__ __launch_bounds__(256) void k_att0_partial(
    const float* __restrict__ lg0, const float* __restrict__ v, int N,
    float* __restrict__ part)
{
    int tid = threadIdx.x, b = blockIdx.x;
    int chunk = (N + ATT0_BLOCKS - 1) / ATT0_BLOCKS;
    int n0 = b * chunk, n1 = min(N, n0 + chunk);
    int h = tid >> 5;
    float acc = 0.f, dacc = 0.f;
    for (int n = n0; n < n1; ++n) {
        float e = expf(lg0[(size_t)n * 8 + h]);
        acc += e * v[(size_t)n * 256 + tid];
        if ((tid & 31) == 0) dacc += e;
    }
    part[b * 264 + tid] = acc;
    if ((tid & 31) == 0) part[b * 264 + 256 + h] = dacc;
}

// ---------------------------------------------------------------------------
// K3b: reduce partials -> att0, then att0f = blk2(att0, pe2[0])
// ---------------------------------------------------------------------------
__global__ __launch_bounds__(256) void k_att0_final(
    const float* __restrict__ part,
    const float* __restrict__ m2W1, const float* __restrict__ m2W2,
    const float* __restrict__ m2b2,
    const float* __restrict__ n2g, const float* __restrict__ n2b,
    const float* __restrict__ c2, float* __restrict__ att0f)
{
    __shared__ float L[256], H[256], red[16], dsh[8];
    int tid = threadIdx.x;
    float s = 0.f;
    for (int b = 0; b < ATT0_BLOCKS; ++b) s += part[b * 264 + tid];
    if (tid < 8) {
        float d = 0.f;
        for (int b = 0; b < ATT0_BLOCKS; ++b) d += part[b * 264 + 256 + tid];
        dsh[tid] = d;
    }
    __syncthreads();
    float a = s / dsh[tid >> 5];
    // LN(n2)
    float ss = a, sq = a * a;
    for (int off = 32; off; off >>= 1) { ss += __shfl_down(ss, off); sq += __shfl_down(sq, off); }
    int lane = tid & 63, wid = tid >> 6;
    if (lane == 0) { red[wid] = ss; red[4 + wid] = sq; }
    __syncthreads();
    if (tid == 0) {
        float S1 = red[0] + red[1] + red[2] + red[3];
        float S2 = red[4] + red[5] + red[6] + red[7];
        float mean = S1 / 256.f, var = S2 / 256.f - mean * mean;
        red[8] = mean; red[9] = rsqrtf(var + 1e-5f);
    }
    __syncthreads();
    L[tid] = (a - red[8]) * red[9] * n2g[tid] + n2b[tid];
    __syncthreads();
    float acc = c2[tid]; // row 0 (includes m2_b1)
    for (int d = 0; d < 256; ++d) acc += L[d] * m2W1[d * 256 + tid];
    H[tid] = gelu_f(acc);
    __syncthreads();
    float acc2 = m2b2[tid];
    for (int d = 0; d < 256; ++d) acc2 += H[d] * m2W2[d * 256 + tid];
    att0f[tid] = a + acc2;
}

// ---------------------------------------------------------------------------
// K4: order-1 per-edge segment softmax + weighted v gather (K=8, contiguous)
// ---------------------------------------------------------------------------
__global__ __launch_bounds__(256) void k_att1e(
    const int* __restrict__ node_idx, const float* __restrict__ lg1,
    const float* __restrict__ v, float* __restrict__ oute)
{
    __shared__ int nid[8];
    __shared__ float lgS[64];
    int e = blockIdx.x, tid = threadIdx.x;
    if (tid < 8) nid[tid] = node_idx[e * 8 + tid];
    __syncthreads();
    if (tid < 64) { int i = tid >> 3, h = tid & 7; lgS[i * 8 + h] = lg1[(size_t)nid[i] * 8 + h]; }
    __syncthreads();
    int h = tid >> 5;
    float m = -1e30f;
    #pragma unroll
    for (int i = 0; i < 8; ++i) m = fmaxf(m, lgS[i * 8 + h]);
    float w[8], den = 0.f;
    #pragma unroll
    for (int i = 0; i < 8; ++i) { w[i] = expf(lgS[i * 8 + h] - m); den += w[i]; }
    float acc = 0.f;
    #pragma unroll
    for (int i = 0; i < 8; ++i) acc += w[i] * v[(size_t)nid[i] * 256 + tid];
    oute[(size_t)e * 256 + tid] = acc / den;
}

// ---------------------------------------------------------------------------
// K5/K6: fused blk2 + att0 add + blk3 + bias, per 16-row tile, in-place ok
// ---------------------------------------------------------------------------
__global__ __launch_bounds__(256) void k_blk23(
    const float* __restrict__ in, float* __restrict__ outp, int M,
    const float* __restrict__ m2W1, const float* __restrict__ m2W2, const float* __restrict__ m2b2,
    const float* __restrict__ m3W1, const float* __restrict__ m3W2, const float* __restrict__ m3b2,
    const float* __restrict__ n2g, const float* __restrict__ n2b,
    const float* __restrict__ n3g, const float* __restrict__ n3b,
    const float* __restrict__ c2row, const float* __restrict__ c3tab,
    const float* __restrict__ att0f, const float* __restrict__ ball,
    const int* __restrict__ orders)
{
    __shared__ __align__(16) float S[TM * 768 + TM * 32 + TM * 2];
    __shared__ int ords[TM];
    float* A = S;
    float* B = S + TM * 256;
    float* C = S + TM * 512;
    float* P = S + TM * 768;
    float* MV = S + TM * 800;

    int tid = threadIdx.x;
    int rg = tid >> 7, cg = tid & 127;
    int row0 = blockIdx.x * TM;

    for (int r = 0; r < TM; ++r) {
        int n = row0 + r;
        A[r * 256 + tid] = (n < M) ? in[(size_t)n * 256 + tid] : 0.f;
    }
    if (tid < TM) {
        int n = row0 + tid;
        ords[tid] = (n < M) ? (orders ? orders[n] : 1) : 1;
    }
    __syncthreads();

    float acc0[8], acc1[8];
    // ---- blk2 ----
    ln_tile(A, B, P, MV, n2g, n2b, tid);
    __syncthreads();
    gemm_tile(B, m2W1, 256, rg, cg, acc0, acc1);   // top half of m2_W1
    {
        float c0 = c2row[cg * 2], c1 = c2row[cg * 2 + 1];
        #pragma unroll
        for (int i = 0; i < 8; ++i) {
            int r = rg * 8 + i;
            C[r * 256 + cg * 2]     = gelu_f(acc0[i] + c0);
            C[r * 256 + cg * 2 + 1] = gelu_f(acc1[i] + c1);
        }
    }
    __syncthreads();
    gemm_tile(C, m2W2, 256, rg, cg, acc0, acc1);
    {
        float b0 = m2b2[cg * 2] + att0f[cg * 2];
        float b1v = m2b2[cg * 2 + 1] + att0f[cg * 2 + 1];
        #pragma unroll
        for (int i = 0; i < 8; ++i) {
            int r = rg * 8 + i;
            A[r * 256 + cg * 2]     += acc0[i] + b0;
            A[r * 256 + cg * 2 + 1] += acc1[i] + b1v;
        }
    }
    __syncthreads();
    // ---- blk3 ----
    ln_tile(A, B, P, MV, n3g, n3b, tid);
    __syncthreads();
    gemm_tile(B, m3W1, 256, rg, cg, acc0, acc1);   // top half of m3_W1
    {
        #pragma unroll
        for (int i = 0; i < 8; ++i) {
            int r = rg * 8 + i;
            const float* c3r = c3tab + (size_t)ords[r] * 256;
            C[r * 256 + cg * 2]     = gelu_f(acc0[i] + c3r[cg * 2]);
            C[r * 256 + cg * 2 + 1] = gelu_f(acc1[i] + c3r[cg * 2 + 1]);
        }
    }
    __syncthreads();
    gemm_tile(C, m3W2, 256, rg, cg, acc0, acc1);
    {
        float b0 = m3b2[cg * 2], b1v = m3b2[cg * 2 + 1];
        #pragma unroll
        for (int i = 0; i < 8; ++i) {
            int r = rg * 8 + i;
            int n = row0 + r;
            if (n < M) {
                const float* br = ball + (size_t)ords[r] * 256;
                outp[(size_t)n * 256 + cg * 2]     = A[r * 256 + cg * 2]     + acc0[i] + b0  + br[cg * 2];
                outp[(size_t)n * 256 + cg * 2 + 1] = A[r * 256 + cg * 2 + 1] + acc1[i] + b1v + br[cg * 2 + 1];
            }
        }
    }
}

extern "C" void kernel_launch(void* const* d_in, const int* in_sizes, int n_in,
                              void* d_out, int out_size, void* d_ws, size_t ws_size,
                              hipStream_t stream)
{
    const float* x          = (const float*)d_in[0];
    const int*   node_idx   = (const int*)d_in[1];
    // d_in[2] edge_idx: repeat(arange(E),8) -> segments are contiguous 8-blocks
    const int*   edge_orders= (const int*)d_in[3];
    const float* qW1 = (const float*)d_in[4];
    const float* qb1 = (const float*)d_in[5];
    const float* qW2 = (const float*)d_in[6];
    const float* qb2 = (const float*)d_in[7];
    const float* kW  = (const float*)d_in[8];
    const float* kb  = (const float*)d_in[9];
    const float* vW  = (const float*)d_in[10];
    const float* vb  = (const float*)d_in[11];
    const float* m1W1= (const float*)d_in[12];
    const float* m1b1= (const float*)d_in[13];
    const float* m1W2= (const float*)d_in[14];
    const float* m1b2= (const float*)d_in[15];
    const float* m2W1= (const float*)d_in[16];
    const float* m2b1= (const float*)d_in[17];
    const float* m2W2= (const float*)d_in[18];
    const float* m2b2= (const float*)d_in[19];
    const float* m3W1= (const float*)d_in[20];
    const float* m3b1= (const float*)d_in[21];
    const float* m3W2= (const float*)d_in[22];
    const float* m3b2= (const float*)d_in[23];
    const float* n1g = (const float*)d_in[24];
    const float* n1b = (const float*)d_in[25];
    const float* n2g = (const float*)d_in[26];
    const float* n2b = (const float*)d_in[27];
    const float* n3g = (const float*)d_in[28];
    const float* n3b = (const float*)d_in[29];
    const float* bW1 = (const float*)d_in[30];
    const float* bb1 = (const float*)d_in[31];
    const float* bW2 = (const float*)d_in[32];
    const float* bb2 = (const float*)d_in[33];

    int N = in_sizes[0] / 256;
    int E = in_sizes[3];

    float* ws    = (float*)d_ws;
    float* q01   = ws;               // 512
    float* ball  = ws + 512;         // 9*256
    float* c2    = ws + 2816;        // 2*256
    float* c3    = ws + 3328;        // 9*256
    float* att0f = ws + 5632;        // 256
    float* part  = ws + 5888;        // 256*264
    float* lg0   = ws + 73472;       // N*8
    float* lg1   = lg0 + (size_t)N * 8;

    float* v_out = (float*)d_out;                       // [N,256]: v, then x_v
    float* out_e = (float*)d_out + (size_t)N * 256;     // [E,256]: att1_e, then x_e

    k_small<<<22, 256, 0, stream>>>(qW1, qb1, qW2, qb2, bW1, bb1, bW2, bb2,
                                    m2W1, m2b1, m3W1, m3b1, q01, ball, c2, c3);
    k_node<<<(N + TM - 1) / TM, 256, 0, stream>>>(x, m1W1, m1b1, m1W2, m1b2, n1g, n1b,
                                                  kW, kb, vW, vb, q01, v_out, lg0, lg1, N);
    k_att0_partial<<<ATT0_BLOCKS, 256, 0, stream>>>(lg0, v_out, N, part);
    k_att0_final<<<1, 256, 0, stream>>>(part, m2W1, m2W2, m2b2, n2g, n2b, c2, att0f);
    k_att1e<<<E, 256, 0, stream>>>(node_idx, lg1, v_out, out_e);
    k_blk23<<<(N + TM - 1) / TM, 256, 0, stream>>>(v_out, v_out, N,
        m2W1, m2W2, m2b2, m3W1, m3W2, m3b2, n2g, n2b, n3g, n3b,
        c2 + 256, c3, att0f, ball, nullptr);
    k_blk23<<<(E + TM - 1) / TM, 256, 0, stream>>>(out_e, out_e, E,
        m2W1, m2W2, m2b2, m3W1, m3W2, m3b2, n2g, n2b, n3g, n3b,
        c2 + 256, c3, att0f, ball, edge_orders);
}

// Round 2
// 763.295 us; speedup vs baseline: 2.7335x; 2.7335x over previous
//
#include <hip/hip_runtime.h>
#include <math.h>

#define ATT0_BLOCKS 256

typedef __attribute__((ext_vector_type(8))) short short8_t;
typedef __attribute__((ext_vector_type(4))) float f32x4;

__device__ __forceinline__ float gelu_f(float x) {
    return 0.5f * x * (1.0f + erff(x * 0.70710678118654752f));
}

__device__ __forceinline__ float pe_val(int pos, int j, int D) {
    int i2 = j & ~1;
    float freq = expf(-9.210340371976184f * (float)i2 / (float)D); // -ln(10000)
    float arg = (float)pos * freq;
    return (j & 1) ? cosf(arg) : sinf(arg);
}

__device__ __forceinline__ unsigned short f2bf(float f) {
    unsigned u = __float_as_uint(f);
    return (unsigned short)((u + 0x7fffu + ((u >> 16) & 1u)) >> 16);
}

// swizzled bf16 LDS tile helpers: rows of 256 bf16 (512 B), byte ^= (row&7)<<4
__device__ __forceinline__ void st_bf(unsigned short* X2, int row, int col, unsigned short v) {
    int byte = (row * 512 + col * 2) ^ ((row & 7) << 4);
    *(unsigned short*)((char*)X2 + byte) = v;
}
__device__ __forceinline__ short8_t ldA(const unsigned short* X2, int m, int ks, int l) {
    int byte = (m * 512 + ks * 64 + ((l >> 4) << 4)) ^ ((m & 7) << 4);
    return *(const short8_t*)((const char*)X2 + byte);
}

// ---------------------------------------------------------------------------
// Pack fp32 weight [256 x (CT*16)] (row stride ld, starting row row0) into
// fragment-linear bf16: dst[((ks*CT + c)*64 + l)*8 + i] = W[ks*32+(l>>4)*8+i][c*16+(l&15)]
// ---------------------------------------------------------------------------
__global__ __launch_bounds__(256) void k_pack(const float* __restrict__ src,
                                              unsigned short* __restrict__ dst,
                                              int CT, int ld, int row0)
{
    int idx = blockIdx.x * 256 + threadIdx.x;
    if (idx >= 4096 * CT) return;
    int i = idx & 7, l = (idx >> 3) & 63, fc = idx >> 9;
    int c = fc % CT, ks = fc / CT;
    int k = ks * 32 + ((l >> 4) << 3) + i;
    int col = c * 16 + (l & 15);
    dst[idx] = f2bf(src[(size_t)(row0 + k) * ld + col]);
}

// ---------------------------------------------------------------------------
// MFMA stage: wave covers 2 row-tiles (32 rows) x NT col-tiles from ct0.
// X2: swizzled bf16 [32][256] LDS. Wp: packed weights, CT total col tiles.
// ---------------------------------------------------------------------------
template <int NT>
__device__ __forceinline__ void mm_frag(const unsigned short* X2,
                                        const unsigned short* __restrict__ Wp,
                                        int CT, int ct0, int l, f32x4 acc[2][NT])
{
    #pragma unroll
    for (int rt = 0; rt < 2; ++rt)
        #pragma unroll
        for (int t = 0; t < NT; ++t)
            acc[rt][t] = (f32x4){0.f, 0.f, 0.f, 0.f};
    #pragma unroll
    for (int ks = 0; ks < 8; ++ks) {
        short8_t a0 = ldA(X2, (l & 15), ks, l);
        short8_t a1 = ldA(X2, 16 + (l & 15), ks, l);
        #pragma unroll
        for (int t = 0; t < NT; ++t) {
            short8_t b = *(const short8_t*)(Wp + (size_t)((ks * CT + ct0 + t) * 64 + l) * 8);
            acc[0][t] = __builtin_amdgcn_mfma_f32_16x16x32_bf16(a0, b, acc[0][t], 0, 0, 0);
            acc[1][t] = __builtin_amdgcn_mfma_f32_16x16x32_bf16(a1, b, acc[1][t], 0, 0, 0);
        }
    }
}

// LN over fp32 [32][256] LDS tile -> swizzled bf16 X2. Caller syncs before & after.
__device__ __forceinline__ void ln32(const float* A, unsigned short* X2, float* MV,
                                     const float* __restrict__ g,
                                     const float* __restrict__ bvec, int tid)
{
    int l = tid & 15, r0 = tid >> 4;
    float s0 = 0.f, q0 = 0.f, s1 = 0.f, q1 = 0.f;
    #pragma unroll
    for (int i = 0; i < 16; ++i) {
        float v0 = A[r0 * 256 + l + i * 16]; s0 += v0; q0 += v0 * v0;
        float v1 = A[(r0 + 16) * 256 + l + i * 16]; s1 += v1; q1 += v1 * v1;
    }
    #pragma unroll
    for (int off = 1; off < 16; off <<= 1) {
        s0 += __shfl_xor(s0, off); q0 += __shfl_xor(q0, off);
        s1 += __shfl_xor(s1, off); q1 += __shfl_xor(q1, off);
    }
    if (l == 0) {
        float m0 = s0 * (1.f / 256.f), v0 = q0 * (1.f / 256.f) - m0 * m0;
        MV[r0 * 2] = m0; MV[r0 * 2 + 1] = rsqrtf(v0 + 1e-5f);
        float m1 = s1 * (1.f / 256.f), v1 = q1 * (1.f / 256.f) - m1 * m1;
        MV[(r0 + 16) * 2] = m1; MV[(r0 + 16) * 2 + 1] = rsqrtf(v1 + 1e-5f);
    }
    __syncthreads();
    float gg = g[tid], bb = bvec[tid];
    #pragma unroll 4
    for (int r = 0; r < 32; ++r) {
        float v = (A[r * 256 + tid] - MV[r * 2]) * MV[r * 2 + 1] * gg + bb;
        st_bf(X2, r, tid, f2bf(v));
    }
}

// ---------------------------------------------------------------------------
// K1: tiny setup — q rows, bias rows, c2/c3 constant vectors (fp32, unchanged)
// ---------------------------------------------------------------------------
__global__ __launch_bounds__(256) void k_small(
    const float* __restrict__ qW1, const float* __restrict__ qb1,
    const float* __restrict__ qW2, const float* __restrict__ qb2,
    const float* __restrict__ bW1, const float* __restrict__ bb1,
    const float* __restrict__ bW2, const float* __restrict__ bb2,
    const float* __restrict__ m2W1, const float* __restrict__ m2b1,
    const float* __restrict__ m3W1, const float* __restrict__ m3b1,
    float* __restrict__ q01, float* __restrict__ ball,
    float* __restrict__ c2, float* __restrict__ c3)
{
    __shared__ float pe[256];
    __shared__ float h[256];
    int b = blockIdx.x, tid = threadIdx.x;
    if (b < 11) {
        int pos = (b < 2) ? b : (b - 2);
        if (tid < 64) pe[tid] = pe_val(pos, tid, 64);
        __syncthreads();
        const float* W1 = (b < 2) ? qW1 : bW1;
        const float* b1 = (b < 2) ? qb1 : bb1;
        const float* W2 = (b < 2) ? qW2 : bW2;
        const float* b2 = (b < 2) ? qb2 : bb2;
        float acc = b1[tid];
        for (int d = 0; d < 64; ++d) acc += pe[d] * W1[d * 256 + tid];
        h[tid] = gelu_f(acc);
        __syncthreads();
        float acc2 = b2[tid];
        for (int d = 0; d < 256; ++d) acc2 += h[d] * W2[d * 256 + tid];
        if (b < 2) q01[b * 256 + tid] = acc2;
        else ball[(b - 2) * 256 + tid] = acc2;
    } else {
        int pos; const float* W1; const float* b1; float* dst;
        if (b < 13) { pos = b - 11; W1 = m2W1; b1 = m2b1; dst = c2 + pos * 256; }
        else        { pos = b - 13; W1 = m3W1; b1 = m3b1; dst = c3 + pos * 256; }
        pe[tid] = pe_val(pos, tid, 256);
        __syncthreads();
        float acc = b1[tid];
        for (int d = 0; d < 256; ++d) acc += pe[d] * W1[(256 + d) * 256 + tid];
        dst[tid] = acc;
    }
}

// ---------------------------------------------------------------------------
// K2 (MFMA): x1 = x + mlp1(ln(x)); v = x1@vW+vb -> global; logits from kW accs
// ---------------------------------------------------------------------------
__global__ __launch_bounds__(256) void k_node(
    const float* __restrict__ x,
    const unsigned short* __restrict__ m1W1p, const float* __restrict__ m1b1,
    const unsigned short* __restrict__ m1W2p, const float* __restrict__ m1b2,
    const float* __restrict__ n1g, const float* __restrict__ n1b,
    const unsigned short* __restrict__ kWp, const float* __restrict__ kb,
    const unsigned short* __restrict__ vWp, const float* __restrict__ vb,
    const float* __restrict__ q01,
    float* __restrict__ v_out, float* __restrict__ lg0, float* __restrict__ lg1, int N)
{
    __shared__ __align__(16) float A[32 * 256];
    __shared__ __align__(16) unsigned short X2[32 * 256];
    __shared__ float MV[64];

    int tid = threadIdx.x;
    int l = tid & 63, wid = tid >> 6, l15 = l & 15;
    int row0 = blockIdx.x * 32;

    // load x tile (float4)
    {
        const float4* xp = (const float4*)x;
        float4* A4 = (float4*)A;
        #pragma unroll
        for (int i = 0; i < 8; ++i) {
            int j = i * 256 + tid;
            int row = j >> 6, c4 = j & 63;
            int n = row0 + row;
            A4[j] = (n < N) ? xp[(size_t)n * 64 + c4] : (float4){0.f, 0.f, 0.f, 0.f};
        }
    }
    __syncthreads();
    ln32(A, X2, MV, n1g, n1b, tid);
    __syncthreads();

    f32x4 acc[2][4];
    // mlp1 stage 1
    mm_frag<4>(X2, m1W1p, 16, wid * 4, l, acc);
    __syncthreads();
    #pragma unroll
    for (int rt = 0; rt < 2; ++rt)
        #pragma unroll
        for (int t = 0; t < 4; ++t) {
            int col = (wid * 4 + t) * 16 + l15;
            float bb = m1b1[col];
            #pragma unroll
            for (int r = 0; r < 4; ++r) {
                int row = rt * 16 + ((l >> 4) << 2) + r;
                st_bf(X2, row, col, f2bf(gelu_f(acc[rt][t][r] + bb)));
            }
        }
    __syncthreads();
    // mlp1 stage 2: A += ...
    mm_frag<4>(X2, m1W2p, 16, wid * 4, l, acc);
    #pragma unroll
    for (int rt = 0; rt < 2; ++rt)
        #pragma unroll
        for (int t = 0; t < 4; ++t) {
            int col = (wid * 4 + t) * 16 + l15;
            float bb = m1b2[col];
            #pragma unroll
            for (int r = 0; r < 4; ++r) {
                int row = rt * 16 + ((l >> 4) << 2) + r;
                A[row * 256 + col] += acc[rt][t][r] + bb;
            }
        }
    __syncthreads();
    // x1 -> bf16
    #pragma unroll 4
    for (int r = 0; r < 32; ++r) st_bf(X2, r, tid, f2bf(A[r * 256 + tid]));
    __syncthreads();

    // k projection: logits straight from accumulators
    {
        f32x4 acck[2][8];
        mm_frag<8>(X2, kWp, 32, wid * 8, l, acck);
        int which = wid >> 1;
        int h0 = (wid & 1) * 4;
        float lp[2][4][4];
        #pragma unroll
        for (int rt = 0; rt < 2; ++rt)
            #pragma unroll
            for (int r = 0; r < 4; ++r)
                #pragma unroll
                for (int hl = 0; hl < 4; ++hl) lp[rt][r][hl] = 0.f;
        #pragma unroll
        for (int t = 0; t < 8; ++t) {
            int d = ((t & 1) << 4) | l15;
            int h = h0 + (t >> 1);
            int col = (which * 16 + (wid & 1) * 8 + t) * 16 + l15; // global col in [0,512)
            float qv = q01[which * 256 + h * 32 + d];
            float kbv = kb[col];
            #pragma unroll
            for (int rt = 0; rt < 2; ++rt)
                #pragma unroll
                for (int r = 0; r < 4; ++r)
                    lp[rt][r][t >> 1] += qv * (acck[rt][t][r] + kbv);
        }
        #pragma unroll
        for (int off = 1; off < 16; off <<= 1)
            #pragma unroll
            for (int rt = 0; rt < 2; ++rt)
                #pragma unroll
                for (int r = 0; r < 4; ++r)
                    #pragma unroll
                    for (int hl = 0; hl < 4; ++hl)
                        lp[rt][r][hl] += __shfl_xor(lp[rt][r][hl], off);
        if (l15 == 0) {
            float* dst = which ? lg1 : lg0;
            #pragma unroll
            for (int rt = 0; rt < 2; ++rt)
                #pragma unroll
                for (int r = 0; r < 4; ++r) {
                    int n = row0 + rt * 16 + ((l >> 4) << 2) + r;
                    if (n < N)
                        #pragma unroll
                        for (int hl = 0; hl < 4; ++hl)
                            dst[(size_t)n * 8 + h0 + hl] = lp[rt][r][hl] * 0.17677669529663687f;
                }
        }
    }
    // v projection -> global
    mm_frag<4>(X2, vWp, 16, wid * 4, l, acc);
    #pragma unroll
    for (int rt = 0; rt < 2; ++rt)
        #pragma unroll
        for (int t = 0; t < 4; ++t) {
            int col = (wid * 4 + t) * 16 + l15;
            float bb = vb[col];
            #pragma unroll
            for (int r = 0; r < 4; ++r) {
                int n = row0 + rt * 16 + ((l >> 4) << 2) + r;
                if (n < N) v_out[(size_t)n * 256 + col] = acc[rt][t][r] + bb;
            }
        }
}

// ---------------------------------------------------------------------------
// K3: order-0 attention partials (deterministic)
// ---------------------------------------------------------------------------
__global__ __launch_bounds__(256) void k_att0_partial(
    const float* __restrict__ lg0, const float* __restrict__ v, int N,
    float* __restrict__ part)
{
    int tid = threadIdx.x, b = blockIdx.x;
    int chunk = (N + ATT0_BLOCKS - 1) / ATT0_BLOCKS;
    int n0 = b * chunk, n1 = min(N, n0 + chunk);
    int h = tid >> 5;
    float acc = 0.f, dacc = 0.f;
    for (int n = n0; n < n1; ++n) {
        float e = expf(lg0[(size_t)n * 8 + h]);
        acc += e * v[(size_t)n * 256 + tid];
        if ((tid & 31) == 0) dacc += e;
    }
    part[b * 264 + tid] = acc;
    if ((tid & 31) == 0) part[b * 264 + 256 + h] = dacc;
}

__global__ __launch_bounds__(256) void k_att0_final(
    const float* __restrict__ part,
    const float* __restrict__ m2W1, const float* __restrict__ m2W2,
    const float* __restrict__ m2b2,
    const float* __restrict__ n2g, const float* __restrict__ n2b,
    const float* __restrict__ c2, float* __restrict__ att0f)
{
    __shared__ float L[256], H[256], red[16], dsh[8];
    int tid = threadIdx.x;
    float s = 0.f;
    for (int b = 0; b < ATT0_BLOCKS; ++b) s += part[b * 264 + tid];
    if (tid < 8) {
        float d = 0.f;
        for (int b = 0; b < ATT0_BLOCKS; ++b) d += part[b * 264 + 256 + tid];
        dsh[tid] = d;
    }
    __syncthreads();
    float a = s / dsh[tid >> 5];
    float ss = a, sq = a * a;
    for (int off = 32; off; off >>= 1) { ss += __shfl_down(ss, off); sq += __shfl_down(sq, off); }
    int lane = tid & 63, wid = tid >> 6;
    if (lane == 0) { red[wid] = ss; red[4 + wid] = sq; }
    __syncthreads();
    if (tid == 0) {
        float S1 = red[0] + red[1] + red[2] + red[3];
        float S2 = red[4] + red[5] + red[6] + red[7];
        float mean = S1 / 256.f, var = S2 / 256.f - mean * mean;
        red[8] = mean; red[9] = rsqrtf(var + 1e-5f);
    }
    __syncthreads();
    L[tid] = (a - red[8]) * red[9] * n2g[tid] + n2b[tid];
    __syncthreads();
    float acc = c2[tid];
    for (int d = 0; d < 256; ++d) acc += L[d] * m2W1[d * 256 + tid];
    H[tid] = gelu_f(acc);
    __syncthreads();
    float acc2 = m2b2[tid];
    for (int d = 0; d < 256; ++d) acc2 += H[d] * m2W2[d * 256 + tid];
    att0f[tid] = a + acc2;
}

// ---------------------------------------------------------------------------
// K4: per-edge segment softmax + weighted v gather (K=8 contiguous)
// ---------------------------------------------------------------------------
__global__ __launch_bounds__(256) void k_att1e(
    const int* __restrict__ node_idx, const float* __restrict__ lg1,
    const float* __restrict__ v, float* __restrict__ oute)
{
    __shared__ int nid[8];
    __shared__ float lgS[64];
    int e = blockIdx.x, tid = threadIdx.x;
    if (tid < 8) nid[tid] = node_idx[e * 8 + tid];
    __syncthreads();
    if (tid < 64) { int i = tid >> 3, h = tid & 7; lgS[i * 8 + h] = lg1[(size_t)nid[i] * 8 + h]; }
    __syncthreads();
    int h = tid >> 5;
    float m = -1e30f;
    #pragma unroll
    for (int i = 0; i < 8; ++i) m = fmaxf(m, lgS[i * 8 + h]);
    float w[8], den = 0.f;
    #pragma unroll
    for (int i = 0; i < 8; ++i) { w[i] = expf(lgS[i * 8 + h] - m); den += w[i]; }
    float acc = 0.f;
    #pragma unroll
    for (int i = 0; i < 8; ++i) acc += w[i] * v[(size_t)nid[i] * 256 + tid];
    oute[(size_t)e * 256 + tid] = acc / den;
}

// ---------------------------------------------------------------------------
// K5/K6 (MFMA): blk2 + att0 add + blk3 + bias, 32 rows/block, in-place ok
// ---------------------------------------------------------------------------
__global__ __launch_bounds__(256) void k_blk23(
    const float* __restrict__ in, float* __restrict__ outp, int M,
    const unsigned short* __restrict__ m2W1p, const unsigned short* __restrict__ m2W2p,
    const float* __restrict__ m2b2,
    const unsigned short* __restrict__ m3W1p, const unsigned short* __restrict__ m3W2p,
    const float* __restrict__ m3b2,
    const float* __restrict__ n2g, const float* __restrict__ n2b,
    const float* __restrict__ n3g, const float* __restrict__ n3b,
    const float* __restrict__ c2row, const float* __restrict__ c3tab,
    const float* __restrict__ att0f, const float* __restrict__ ball,
    const int* __restrict__ orders)
{
    __shared__ __align__(16) float A[32 * 256];
    __shared__ __align__(16) unsigned short X2[32 * 256];
    __shared__ float MV[64];
    __shared__ int ords[32];

    int tid = threadIdx.x;
    int l = tid & 63, wid = tid >> 6, l15 = l & 15;
    int row0 = blockIdx.x * 32;

    {
        const float4* inp = (const float4*)in;
        float4* A4 = (float4*)A;
        #pragma unroll
        for (int i = 0; i < 8; ++i) {
            int j = i * 256 + tid;
            int row = j >> 6, c4 = j & 63;
            int n = row0 + row;
            A4[j] = (n < M) ? inp[(size_t)n * 64 + c4] : (float4){0.f, 0.f, 0.f, 0.f};
        }
    }
    if (tid < 32) {
        int n = row0 + tid;
        ords[tid] = (n < M && orders) ? orders[n] : 1;
    }
    __syncthreads();

    f32x4 acc[2][4];
    // ---- blk2 ----
    ln32(A, X2, MV, n2g, n2b, tid);
    __syncthreads();
    mm_frag<4>(X2, m2W1p, 16, wid * 4, l, acc);
    __syncthreads();
    #pragma unroll
    for (int rt = 0; rt < 2; ++rt)
        #pragma unroll
        for (int t = 0; t < 4; ++t) {
            int col = (wid * 4 + t) * 16 + l15;
            float bb = c2row[col];
            #pragma unroll
            for (int r = 0; r < 4; ++r) {
                int row = rt * 16 + ((l >> 4) << 2) + r;
                st_bf(X2, row, col, f2bf(gelu_f(acc[rt][t][r] + bb)));
            }
        }
    __syncthreads();
    mm_frag<4>(X2, m2W2p, 16, wid * 4, l, acc);
    #pragma unroll
    for (int rt = 0; rt < 2; ++rt)
        #pragma unroll
        for (int t = 0; t < 4; ++t) {
            int col = (wid * 4 + t) * 16 + l15;
            float bb = m2b2[col] + att0f[col];
            #pragma unroll
            for (int r = 0; r < 4; ++r) {
                int row = rt * 16 + ((l >> 4) << 2) + r;
                A[row * 256 + col] += acc[rt][t][r] + bb;
            }
        }
    __syncthreads();
    // ---- blk3 ----
    ln32(A, X2, MV, n3g, n3b, tid);
    __syncthreads();
    mm_frag<4>(X2, m3W1p, 16, wid * 4, l, acc);
    __syncthreads();
    #pragma unroll
    for (int rt = 0; rt < 2; ++rt)
        #pragma unroll
        for (int t = 0; t < 4; ++t) {
            int col = (wid * 4 + t) * 16 + l15;
            #pragma unroll
            for (int r = 0; r < 4; ++r) {
                int row = rt * 16 + ((l >> 4) << 2) + r;
                float bb = c3tab[ords[row] * 256 + col];
                st_bf(X2, row, col, f2bf(gelu_f(acc[rt][t][r] + bb)));
            }
        }
    __syncthreads();
    mm_frag<4>(X2, m3W2p, 16, wid * 4, l, acc);
    #pragma unroll
    for (int rt = 0; rt < 2; ++rt)
        #pragma unroll
        for (int t = 0; t < 4; ++t) {
            int col = (wid * 4 + t) * 16 + l15;
            float bb = m3b2[col];
            #pragma unroll
            for (int r = 0; r < 4; ++r) {
                int row = rt * 16 + ((l >> 4) << 2) + r;
                int n = row0 + row;
                if (n < M)
                    outp[(size_t)n * 256 + col] =
                        A[row * 256 + col] + acc[rt][t][r] + bb + ball[ords[row] * 256 + col];
            }
        }
}

extern "C" void kernel_launch(void* const* d_in, const int* in_sizes, int n_in,
                              void* d_out, int out_size, void* d_ws, size_t ws_size,
                              hipStream_t stream)
{
    const float* x          = (const float*)d_in[0];
    const int*   node_idx   = (const int*)d_in[1];
    const int*   edge_orders= (const int*)d_in[3];
    const float* qW1 = (const float*)d_in[4];
    const float* qb1 = (const float*)d_in[5];
    const float* qW2 = (const float*)d_in[6];
    const float* qb2 = (const float*)d_in[7];
    const float* kW  = (const float*)d_in[8];
    const float* kb  = (const float*)d_in[9];
    const float* vW  = (const float*)d_in[10];
    const float* vb  = (const float*)d_in[11];
    const float* m1W1= (const float*)d_in[12];
    const float* m1b1= (const float*)d_in[13];
    const float* m1W2= (const float*)d_in[14];
    const float* m1b2= (const float*)d_in[15];
    const float* m2W1= (const float*)d_in[16];
    const float* m2b1= (const float*)d_in[17];
    const float* m2W2= (const float*)d_in[18];
    const float* m2b2= (const float*)d_in[19];
    const float* m3W1= (const float*)d_in[20];
    const float* m3b1= (const float*)d_in[21];
    const float* m3W2= (const float*)d_in[22];
    const float* m3b2= (const float*)d_in[23];
    const float* n1g = (const float*)d_in[24];
    const float* n1b = (const float*)d_in[25];
    const float* n2g = (const float*)d_in[26];
    const float* n2b = (const float*)d_in[27];
    const float* n3g = (const float*)d_in[28];
    const float* n3b = (const float*)d_in[29];
    const float* bW1 = (const float*)d_in[30];
    const float* bb1 = (const float*)d_in[31];
    const float* bW2 = (const float*)d_in[32];
    const float* bb2 = (const float*)d_in[33];

    int N = in_sizes[0] / 256;
    int E = in_sizes[3];

    float* ws    = (float*)d_ws;
    float* q01   = ws;               // 512
    float* ball  = ws + 512;         // 9*256
    float* c2    = ws + 2816;        // 2*256
    float* c3    = ws + 3328;        // 9*256
    float* att0f = ws + 5632;        // 256
    float* part  = ws + 5888;        // 256*264 -> end 73472
    float* lg0   = ws + 73472;       // N*8
    float* lg1   = lg0 + (size_t)N * 8;
    unsigned short* pk = (unsigned short*)(ws + 873472);
    unsigned short* m1W1p = pk;             // 65536
    unsigned short* m1W2p = pk + 65536;
    unsigned short* kWp   = pk + 131072;    // 131072
    unsigned short* vWp   = pk + 262144;
    unsigned short* m2W1p = pk + 327680;
    unsigned short* m2W2p = pk + 393216;
    unsigned short* m3W1p = pk + 458752;
    unsigned short* m3W2p = pk + 524288;    // end 589824 shorts

    float* v_out = (float*)d_out;                       // [N,256]: v, then x_v
    float* out_e = (float*)d_out + (size_t)N * 256;     // [E,256]: att1_e, then x_e

    // weight packing (L2-resident bf16 fragment-linear)
    k_pack<<<16 * 16, 256, 0, stream>>>(m1W1, m1W1p, 16, 256, 0);
    k_pack<<<16 * 16, 256, 0, stream>>>(m1W2, m1W2p, 16, 256, 0);
    k_pack<<<16 * 32, 256, 0, stream>>>(kW,   kWp,   32, 512, 0);
    k_pack<<<16 * 16, 256, 0, stream>>>(vW,   vWp,   16, 256, 0);
    k_pack<<<16 * 16, 256, 0, stream>>>(m2W1, m2W1p, 16, 256, 0);
    k_pack<<<16 * 16, 256, 0, stream>>>(m2W2, m2W2p, 16, 256, 0);
    k_pack<<<16 * 16, 256, 0, stream>>>(m3W1, m3W1p, 16, 256, 0);
    k_pack<<<16 * 16, 256, 0, stream>>>(m3W2, m3W2p, 16, 256, 0);

    k_small<<<22, 256, 0, stream>>>(qW1, qb1, qW2, qb2, bW1, bb1, bW2, bb2,
                                    m2W1, m2b1, m3W1, m3b1, q01, ball, c2, c3);
    k_node<<<(N + 31) / 32, 256, 0, stream>>>(x, m1W1p, m1b1, m1W2p, m1b2, n1g, n1b,
                                              kWp, kb, vWp, vb, q01, v_out, lg0, lg1, N);
    k_att0_partial<<<ATT0_BLOCKS, 256, 0, stream>>>(lg0, v_out, N, part);
    k_att0_final<<<1, 256, 0, stream>>>(part, m2W1, m2W2, m2b2, n2g, n2b, c2, att0f);
    k_att1e<<<E, 256, 0, stream>>>(node_idx, lg1, v_out, out_e);
    k_blk23<<<(N + 31) / 32, 256, 0, stream>>>(v_out, v_out, N,
        m2W1p, m2W2p, m2b2, m3W1p, m3W2p, m3b2, n2g, n2b, n3g, n3b,
        c2 + 256, c3, att0f, ball, nullptr);
    k_blk23<<<(E + 31) / 32, 256, 0, stream>>>(out_e, out_e, E,
        m2W1p, m2W2p, m2b2, m3W1p, m3W2p, m3b2, n2g, n2b, n3g, n3b,
        c2 + 256, c3, att0f, ball, edge_orders);
}